// Round 14
// baseline (188.263 us; speedup 1.0000x reference)
//
#include <hip/hip_runtime.h>

#define T_STEPS 256
#define IMG 512
#define HW (IMG * IMG)
#define TW 32
#define TH 8
#define HTW 40                 // dwords per halo row (cols -4..35) = 10 chunks
#define HTH 12                 // halo rows -2..9
#define NCHK 120               // real 16B chunks per frame
#define BUF_DW 512             // 128 chunks (8 dummy) * 4 dwords per frame buffer
#define NBUF 12                // ring of 12 frame buffers = 24 KiB LDS

// Zero page for fully-OOB halo chunks (device global: never written, stays 0).
__device__ __align__(16) float g_zeropage[8] = {0, 0, 0, 0, 0, 0, 0, 0};

typedef const __attribute__((address_space(1))) unsigned int* gptr_t;
typedef __attribute__((address_space(3))) unsigned int* lptr_t;
typedef float vf4 __attribute__((ext_vector_type(4)));
typedef float vf2 __attribute__((ext_vector_type(2)));

// out[t] = 0.8*out[t-1] + conv(x)[t-1]; out[0]=0 — conv and LI scan commute.
// R12 champion memory structure (single-wave blocks, no barriers, glds DMA,
// ring-12, counted vmcnt never touching stores) with the output grid SHIFTED
// +2 cols: lane q outputs cols 4q+2..4q+5, window = cols 4q..4q+7 = chunks
// q+1,q+2 -> exactly 2 aligned ds_read_b128/row (10/step, was 15). Edges:
// cols 512/513 land in the auto-zero OOB chunk (= correct zero-pad for
// outputs 510/511; bogus o2/o3 not stored); cols 0/1 computed by bx==0
// blocks via truncated-tap pk_fma (zero-pad exact).
__launch_bounds__(64)
__global__ void conv_li_kernel(const float* __restrict__ x,
                               const float* __restrict__ kern,
                               float* __restrict__ out) {
    __shared__ __align__(16) float lds[NBUF][BUF_DW];
    const int tid = threadIdx.x;
    const int bid = blockIdx.x;
    // 1024 blocks over 8 XCDs (bijective): vertical halo sharing stays per-XCD L2.
    const int vbid = (bid & 7) * 128 + (bid >> 3);
    const int bx = vbid & 15;      // 16 tiles across
    const int by = vbid >> 4;      // 64 tile rows

    // 5x5 kernel -> wave-uniform (SGPR) weights.
    float kw[25];
#pragma unroll
    for (int i = 0; i < 25; ++i)
        kw[i] = __int_as_float(__builtin_amdgcn_readfirstlane(__float_as_int(kern[i])));

    // DMA source chunks (identical to R7/R12 champion).
    const float* srcA; const float* srcB; bool okA, okB;
    {
        int c = tid;
        int row = c / 10, cc = c - row * 10;
        int gy = by * TH + row - 2, gx = bx * TW + cc * 4 - 4;
        okA = (gy >= 0) && (gy < IMG) && (gx >= 0) && (gx <= IMG - 4);
        srcA = x + (size_t)(okA ? gy : 0) * IMG + (okA ? gx : 0);
        c = tid + 64;
        row = c / 10; cc = c - row * 10;
        gy = by * TH + row - 2; gx = bx * TW + cc * 4 - 4;
        okB = (c < NCHK) && (gy >= 0) && (gy < IMG) && (gx >= 0) && (gx <= IMG - 4);
        srcB = x + (size_t)(okB ? gy : 0) * IMG + (okB ? gx : 0);
    }

    auto GLDS = [&](int bi, int tf) {
        const float* pA = okA ? srcA + (size_t)tf * HW : g_zeropage;
        const float* pB = okB ? srcB + (size_t)tf * HW : g_zeropage;
        __builtin_amdgcn_global_load_lds((gptr_t)pA, (lptr_t)&lds[bi][0], 16, 0, 0);
        __builtin_amdgcn_global_load_lds((gptr_t)pB, (lptr_t)&lds[bi][256], 16, 0, 0);
    };
    auto BATCH = [&](int bufbase, int f0) {   // 4 frames = 8 glds, issued in order
#pragma unroll
        for (int j = 0; j < 4; ++j) {
            int tf = f0 + j; if (tf > T_STEPS - 1) tf = T_STEPS - 1;
            GLDS(bufbase + j, tf);
        }
    };

    const int q = tid & 7;         // col-quad: outputs cols 4q+2..4q+5
    const int rr = tid >> 3;       // out row within tile
    const bool lastq = (bx == 15) && (q == 7);   // drop cols 512,513
    const bool edgeblk = (bx == 0);              // computes cols 0,1 too
    const size_t rowbase = (size_t)(by * TH + rr) * IMG;
    const size_t obase = rowbase + bx * TW + 4 * q + 2;

    vf2 stP = {0.f, 0.f}, stQ = {0.f, 0.f};   // cols 4q+2,3 and 4q+4,5
    vf2 stE = {0.f, 0.f};                      // cols 0,1 (bx==0, q==0 lanes)

    auto STEP = [&](int bi, int t) {
        vf2 A0 = {0.f, 0.f}, A1 = {0.f, 0.f}, A2 = {0.f, 0.f}, A3 = {0.f, 0.f};
        vf2 AE0 = {0.f, 0.f}, AE1 = {0.f, 0.f};
        // Window cols 4q..4q+7 = chunks q+1, q+2 of halo row rr+dy.
        const float* Bp = &lds[bi][(rr * 10 + q + 1) * 4];
#pragma unroll
        for (int dy = 0; dy < 5; ++dy) {
            const float* L = Bp + dy * HTW;
            vf4 c0 = *(const vf4*)(L);        // w0..w3 = cols 4q..4q+3
            vf4 c1 = *(const vf4*)(L + 4);    // w4..w7 = cols 4q+4..4q+7
            vf2 P0 = {c0.x, c0.y};
            vf2 P1 = {c0.z, c0.w};
            vf2 P2 = {c1.x, c1.y};
            vf2 P3 = {c1.z, c1.w};
            const float k0 = kw[dy * 5 + 0], k1 = kw[dy * 5 + 1], k2 = kw[dy * 5 + 2];
            const float k3 = kw[dy * 5 + 3], k4 = kw[dy * 5 + 4];
            const vf2 K01 = {k0, k1}, K23 = {k2, k3}, K40 = {k4, 0.f};
            const vf2 K0h = {0.f, k0}, K12 = {k1, k2}, K34 = {k3, k4};
            // o0 (col 4q+2) = k·w[0..4]; o1 = k·w[1..5]; o2 = k·w[2..6]; o3 = k·w[3..7]
            A0 = __builtin_elementwise_fma(K01, P0, A0);
            A0 = __builtin_elementwise_fma(K23, P1, A0);
            A0 = __builtin_elementwise_fma(K40, P2, A0);
            A1 = __builtin_elementwise_fma(K0h, P0, A1);
            A1 = __builtin_elementwise_fma(K12, P1, A1);
            A1 = __builtin_elementwise_fma(K34, P2, A1);
            A2 = __builtin_elementwise_fma(K01, P1, A2);
            A2 = __builtin_elementwise_fma(K23, P2, A2);
            A2 = __builtin_elementwise_fma(K40, P3, A2);
            A3 = __builtin_elementwise_fma(K0h, P1, A3);
            A3 = __builtin_elementwise_fma(K12, P2, A3);
            A3 = __builtin_elementwise_fma(K34, P3, A3);
            if (edgeblk) {
                // col 0: window -2..2 -> k2..k4 on w0..w2; col 1: k1..k4 on w0..w3
                AE0 = __builtin_elementwise_fma(K23, P0, AE0);
                AE0 = __builtin_elementwise_fma(K40, P1, AE0);
                AE1 = __builtin_elementwise_fma(K12, P0, AE1);
                AE1 = __builtin_elementwise_fma(K34, P1, AE1);
            }
        }
        float* op = out + (size_t)t * HW + obase;
        __builtin_nontemporal_store(stP, (vf2*)op);          // cols 4q+2,3
        if (!lastq)
            __builtin_nontemporal_store(stQ, (vf2*)(op + 2)); // cols 4q+4,5
        if (edgeblk) {
            if (q == 0)
                __builtin_nontemporal_store(stE, (vf2*)(out + (size_t)t * HW + rowbase));
            vf2 accE = {AE0.x + AE0.y, AE1.x + AE1.y};
            const vf2 m02e = {-0.2f, -0.2f};
            stE = __builtin_elementwise_fma(m02e, stE, stE) + accE;
        }
        vf2 accP = {A0.x + A0.y, A1.x + A1.y};
        vf2 accQ = {A2.x + A2.y, A3.x + A3.y};
        const vf2 m02 = {-0.2f, -0.2f};
        stP = __builtin_elementwise_fma(m02, stP, stP) + accP;   // 0.8*S + y
        stQ = __builtin_elementwise_fma(m02, stQ, stQ) + accQ;
    };

    // Prologue: frames 0..7 in flight (16 glds).
    BATCH(0, 0);
    BATCH(4, 4);

    // Group 0 (frames 0..3): outstanding 16, need oldest 8 -> vmcnt(8).
    asm volatile("s_waitcnt vmcnt(8)" ::: "memory");
    STEP(0, 0); STEP(1, 1); STEP(2, 2); STEP(3, 3);
    BATCH(8, 8);

    // Steady state: newer-than-target-batch = stores(8) + next batch(8) = 16;
    // waited batch is oldest -> vmcnt(16) never touches stores.
#pragma clang loop unroll(disable)
    for (int sg = 0; sg < 21; ++sg) {
        const int t0 = 4 + sg * 12;
        asm volatile("s_waitcnt vmcnt(16)" ::: "memory");
        STEP(4, t0 + 0); STEP(5, t0 + 1); STEP(6, t0 + 2); STEP(7, t0 + 3);
        BATCH(0, t0 + 8);
        asm volatile("s_waitcnt vmcnt(16)" ::: "memory");
        STEP(8, t0 + 4); STEP(9, t0 + 5); STEP(10, t0 + 6); STEP(11, t0 + 7);
        BATCH(4, t0 + 12);
        asm volatile("s_waitcnt vmcnt(16)" ::: "memory");
        STEP(0, t0 + 8); STEP(1, t0 + 9); STEP(2, t0 + 10); STEP(3, t0 + 11);
        BATCH(8, t0 + 16);
    }
}

extern "C" void kernel_launch(void* const* d_in, const int* in_sizes, int n_in,
                              void* d_out, int out_size, void* d_ws, size_t ws_size,
                              hipStream_t stream) {
    const float* x = (const float*)d_in[0];      // [256,1,512,512] f32
    const float* kern = (const float*)d_in[1];   // [5,5] f32
    float* out = (float*)d_out;                  // [256,1,512,512] f32

    conv_li_kernel<<<dim3(1024), dim3(64), 0, stream>>>(x, kern, out);
}

// Round 15
// 170.131 us; speedup vs baseline: 1.1066x; 1.1066x over previous
//
#include <hip/hip_runtime.h>

#define T_STEPS 256
#define IMG 512
#define HW (IMG * IMG)
#define TW 32
#define TH 8
#define HTW 40                 // dwords per halo row (cols -4..35) = 10 chunks
#define HTH 12                 // halo rows -2..9
#define NCHK 120               // real 16B chunks per frame
#define BUF_DW 512             // 128 chunks (8 dummy) * 4 dwords per frame buffer
#define NBUF 8                 // ring of 8 frame buffers = 16 KiB LDS

// Zero page for fully-OOB halo chunks (device global: never written, stays 0).
__device__ __align__(16) float g_zeropage[8] = {0, 0, 0, 0, 0, 0, 0, 0};

typedef const __attribute__((address_space(1))) unsigned int* gptr_t;
typedef __attribute__((address_space(3))) unsigned int* lptr_t;
typedef float vf4 __attribute__((ext_vector_type(4)));
typedef float vf2 __attribute__((ext_vector_type(2)));

// out[t] = 0.8*out[t-1] + conv(x)[t-1]; out[0]=0 — conv and LI scan commute.
// Single-wave blocks, no barriers, glds DMA staging, counted vmcnt never
// touching stores. Output grid shifted +2 cols: lane q outputs cols 4q+2..
// 4q+5, window = chunks q+1,q+2 -> exactly 2 aligned ds_read_b128/row
// (10/step vs 15). Stores are PLAIN vf2 (L2 write-merge; R14's nt-vf2
// caused 430MB write amplification + store-queue stalls). NBUF=8.
__launch_bounds__(64)
__global__ void conv_li_kernel(const float* __restrict__ x,
                               const float* __restrict__ kern,
                               float* __restrict__ out) {
    __shared__ __align__(16) float lds[NBUF][BUF_DW];
    const int tid = threadIdx.x;
    const int bid = blockIdx.x;
    // 1024 blocks over 8 XCDs (bijective): vertical halo sharing stays per-XCD L2.
    const int vbid = (bid & 7) * 128 + (bid >> 3);
    const int bx = vbid & 15;      // 16 tiles across
    const int by = vbid >> 4;      // 64 tile rows

    // 5x5 kernel -> wave-uniform (SGPR) weights.
    float kw[25];
#pragma unroll
    for (int i = 0; i < 25; ++i)
        kw[i] = __int_as_float(__builtin_amdgcn_readfirstlane(__float_as_int(kern[i])));

    // DMA source chunks (identical to champion).
    const float* srcA; const float* srcB; bool okA, okB;
    {
        int c = tid;
        int row = c / 10, cc = c - row * 10;
        int gy = by * TH + row - 2, gx = bx * TW + cc * 4 - 4;
        okA = (gy >= 0) && (gy < IMG) && (gx >= 0) && (gx <= IMG - 4);
        srcA = x + (size_t)(okA ? gy : 0) * IMG + (okA ? gx : 0);
        c = tid + 64;
        row = c / 10; cc = c - row * 10;
        gy = by * TH + row - 2; gx = bx * TW + cc * 4 - 4;
        okB = (c < NCHK) && (gy >= 0) && (gy < IMG) && (gx >= 0) && (gx <= IMG - 4);
        srcB = x + (size_t)(okB ? gy : 0) * IMG + (okB ? gx : 0);
    }

    auto GLDS = [&](int bi, int tf) {
        const float* pA = okA ? srcA + (size_t)tf * HW : g_zeropage;
        const float* pB = okB ? srcB + (size_t)tf * HW : g_zeropage;
        __builtin_amdgcn_global_load_lds((gptr_t)pA, (lptr_t)&lds[bi][0], 16, 0, 0);
        __builtin_amdgcn_global_load_lds((gptr_t)pB, (lptr_t)&lds[bi][256], 16, 0, 0);
    };
    auto BATCH = [&](int bufbase, int f0) {   // 4 frames = 8 glds, issued in order
#pragma unroll
        for (int j = 0; j < 4; ++j) {
            int tf = f0 + j; if (tf > T_STEPS - 1) tf = T_STEPS - 1;
            GLDS(bufbase + j, tf);
        }
    };

    const int q = tid & 7;         // col-quad: outputs cols 4q+2..4q+5
    const int rr = tid >> 3;       // out row within tile
    const bool lastq = (bx == 15) && (q == 7);   // drop cols 512,513
    const bool edgeblk = (bx == 0);              // computes cols 0,1 too
    const size_t rowbase = (size_t)(by * TH + rr) * IMG;
    const size_t obase = rowbase + bx * TW + 4 * q + 2;

    vf2 stP = {0.f, 0.f}, stQ = {0.f, 0.f};   // cols 4q+2,3 and 4q+4,5
    vf2 stE = {0.f, 0.f};                      // cols 0,1 (bx==0, q==0 lanes)

    auto STEP = [&](int bi, int t) {
        vf2 A0 = {0.f, 0.f}, A1 = {0.f, 0.f}, A2 = {0.f, 0.f}, A3 = {0.f, 0.f};
        vf2 AE0 = {0.f, 0.f}, AE1 = {0.f, 0.f};
        // Window cols 4q..4q+7 = chunks q+1, q+2 of halo row rr+dy.
        const float* Bp = &lds[bi][(rr * 10 + q + 1) * 4];
#pragma unroll
        for (int dy = 0; dy < 5; ++dy) {
            const float* L = Bp + dy * HTW;
            vf4 c0 = *(const vf4*)(L);        // w0..w3 = cols 4q..4q+3
            vf4 c1 = *(const vf4*)(L + 4);    // w4..w7 = cols 4q+4..4q+7
            vf2 P0 = {c0.x, c0.y};
            vf2 P1 = {c0.z, c0.w};
            vf2 P2 = {c1.x, c1.y};
            vf2 P3 = {c1.z, c1.w};
            const float k0 = kw[dy * 5 + 0], k1 = kw[dy * 5 + 1], k2 = kw[dy * 5 + 2];
            const float k3 = kw[dy * 5 + 3], k4 = kw[dy * 5 + 4];
            const vf2 K01 = {k0, k1}, K23 = {k2, k3}, K40 = {k4, 0.f};
            const vf2 K0h = {0.f, k0}, K12 = {k1, k2}, K34 = {k3, k4};
            // o0 (col 4q+2) = k·w[0..4]; o1 = k·w[1..5]; o2 = k·w[2..6]; o3 = k·w[3..7]
            A0 = __builtin_elementwise_fma(K01, P0, A0);
            A0 = __builtin_elementwise_fma(K23, P1, A0);
            A0 = __builtin_elementwise_fma(K40, P2, A0);
            A1 = __builtin_elementwise_fma(K0h, P0, A1);
            A1 = __builtin_elementwise_fma(K12, P1, A1);
            A1 = __builtin_elementwise_fma(K34, P2, A1);
            A2 = __builtin_elementwise_fma(K01, P1, A2);
            A2 = __builtin_elementwise_fma(K23, P2, A2);
            A2 = __builtin_elementwise_fma(K40, P3, A2);
            A3 = __builtin_elementwise_fma(K0h, P1, A3);
            A3 = __builtin_elementwise_fma(K12, P2, A3);
            A3 = __builtin_elementwise_fma(K34, P3, A3);
            if (edgeblk) {
                // col 0: k2..k4 on w0..w2; col 1: k1..k4 on w0..w3 (zero-pad exact)
                AE0 = __builtin_elementwise_fma(K23, P0, AE0);
                AE0 = __builtin_elementwise_fma(K40, P1, AE0);
                AE1 = __builtin_elementwise_fma(K12, P0, AE1);
                AE1 = __builtin_elementwise_fma(K34, P1, AE1);
            }
        }
        float* op = out + (size_t)t * HW + obase;
        *(vf2*)op = stP;                        // cols 4q+2,3 (plain: L2 merges)
        if (!lastq)
            *(vf2*)(op + 2) = stQ;              // cols 4q+4,5
        if (edgeblk) {
            if (q == 0)
                *(vf2*)(out + (size_t)t * HW + rowbase) = stE;   // cols 0,1
            vf2 accE = {AE0.x + AE0.y, AE1.x + AE1.y};
            const vf2 m02e = {-0.2f, -0.2f};
            stE = __builtin_elementwise_fma(m02e, stE, stE) + accE;
        }
        vf2 accP = {A0.x + A0.y, A1.x + A1.y};
        vf2 accQ = {A2.x + A2.y, A3.x + A3.y};
        const vf2 m02 = {-0.2f, -0.2f};
        stP = __builtin_elementwise_fma(m02, stP, stP) + accP;   // 0.8*S + y
        stQ = __builtin_elementwise_fma(m02, stQ, stQ) + accQ;
    };

    // Prologue: B0 (bufs 0-3 <- frames 0-3), B1 (bufs 4-7 <- frames 4-7).
    BATCH(0, 0);
    BATCH(4, 4);

    // Group 0: outstanding B0(8)+B1(8)=16; need B0 -> vmcnt(8).
    asm volatile("s_waitcnt vmcnt(8)" ::: "memory");
    STEP(0, 0); STEP(1, 1); STEP(2, 2); STEP(3, 3);
    BATCH(0, 8);   // B2 overwrites bufs 0-3

    // Steady (g>=1): queue old->new = B_g(8), S_{g-1}(8), B_{g+1}(8) ->
    // vmcnt(16) drains exactly B_g; stores never waited.
#pragma clang loop unroll(disable)
    for (int g = 1; g < 64; ++g) {
        const int bb = (g & 1) * 4;
        const int t0 = g * 4;
        asm volatile("s_waitcnt vmcnt(16)" ::: "memory");
        STEP(bb + 0, t0 + 0); STEP(bb + 1, t0 + 1);
        STEP(bb + 2, t0 + 2); STEP(bb + 3, t0 + 3);
        BATCH(bb, t0 + 8);
    }
}

extern "C" void kernel_launch(void* const* d_in, const int* in_sizes, int n_in,
                              void* d_out, int out_size, void* d_ws, size_t ws_size,
                              hipStream_t stream) {
    const float* x = (const float*)d_in[0];      // [256,1,512,512] f32
    const float* kern = (const float*)d_in[1];   // [5,5] f32
    float* out = (float*)d_out;                  // [256,1,512,512] f32

    conv_li_kernel<<<dim3(1024), dim3(64), 0, stream>>>(x, kern, out);
}

// Round 16
// 97.307 us; speedup vs baseline: 1.9347x; 1.7484x over previous
//
#include <hip/hip_runtime.h>

#define T_STEPS 256
#define IMG 512
#define HW (IMG * IMG)
#define TW 32
#define TH 8
#define HTW 40                 // dwords per halo row (cols -4..35) = 10 chunks
#define HTH 12                 // halo rows -2..9
#define NCHK 120               // real 16B chunks per frame
#define BUF_DW 512             // 128 chunks (8 dummy) * 4 dwords per frame buffer
#define NBUF 12                // ring of 12 frame buffers = 24 KiB LDS

// Zero page for fully-OOB halo chunks (device global: never written, stays 0).
__device__ __align__(16) float g_zeropage[8] = {0, 0, 0, 0, 0, 0, 0, 0};

typedef const __attribute__((address_space(1))) unsigned int* gptr_t;
typedef __attribute__((address_space(3))) unsigned int* lptr_t;
typedef float vf4 __attribute__((ext_vector_type(4)));
typedef float vf2 __attribute__((ext_vector_type(2)));

// out[t] = 0.8*out[t-1] + conv(x)[t-1]; out[0]=0 — conv and LI scan commute.
// R12 champion memory structure EXACTLY (single-wave blocks, no barriers,
// glds DMA, ring-12, counted vmcnt never touching stores, nt dwordx4 stores,
// pk_fma conv). NEW: LDS reads software-pipelined ONE FULL STEP ahead via
// double-buffered register window (WA/WB, 15 vf4 each): while step t's FMAs
// run, step t+1's rows load in a 1:1 {load-row || fma-row} interleave ->
// ~130-cyc lookahead covers DS latency; outstanding DS <= ~9 (< lgkmcnt 15).
__launch_bounds__(64)
__global__ void conv_li_kernel(const float* __restrict__ x,
                               const float* __restrict__ kern,
                               float* __restrict__ out) {
    __shared__ __align__(16) float lds[NBUF][BUF_DW];
    const int tid = threadIdx.x;
    const int bid = blockIdx.x;
    // 1024 blocks over 8 XCDs (bijective): vertical halo sharing stays per-XCD L2.
    const int vbid = (bid & 7) * 128 + (bid >> 3);
    const int bx = vbid & 15;      // 16 tiles across
    const int by = vbid >> 4;      // 64 tile rows

    // 5x5 kernel -> wave-uniform (SGPR) weights.
    float kw[25];
#pragma unroll
    for (int i = 0; i < 25; ++i)
        kw[i] = __int_as_float(__builtin_amdgcn_readfirstlane(__float_as_int(kern[i])));

    // DMA source chunks (identical to champion).
    const float* srcA; const float* srcB; bool okA, okB;
    {
        int c = tid;
        int row = c / 10, cc = c - row * 10;
        int gy = by * TH + row - 2, gx = bx * TW + cc * 4 - 4;
        okA = (gy >= 0) && (gy < IMG) && (gx >= 0) && (gx <= IMG - 4);
        srcA = x + (size_t)(okA ? gy : 0) * IMG + (okA ? gx : 0);
        c = tid + 64;
        row = c / 10; cc = c - row * 10;
        gy = by * TH + row - 2; gx = bx * TW + cc * 4 - 4;
        okB = (c < NCHK) && (gy >= 0) && (gy < IMG) && (gx >= 0) && (gx <= IMG - 4);
        srcB = x + (size_t)(okB ? gy : 0) * IMG + (okB ? gx : 0);
    }

    auto GLDS = [&](int bi, int tf) {
        const float* pA = okA ? srcA + (size_t)tf * HW : g_zeropage;
        const float* pB = okB ? srcB + (size_t)tf * HW : g_zeropage;
        __builtin_amdgcn_global_load_lds((gptr_t)pA, (lptr_t)&lds[bi][0], 16, 0, 0);
        __builtin_amdgcn_global_load_lds((gptr_t)pB, (lptr_t)&lds[bi][256], 16, 0, 0);
    };
    auto BATCH = [&](int bufbase, int f0) {   // 4 frames = 8 glds, issued in order
#pragma unroll
        for (int j = 0; j < 4; ++j) {
            int tf = f0 + j; if (tf > T_STEPS - 1) tf = T_STEPS - 1;
            GLDS(bufbase + j, tf);
        }
    };

    const int q = tid & 7;         // col-quad (4 out cols)
    const int rr = tid >> 3;       // out row within tile
    const size_t obase = (size_t)(by * TH + rr) * IMG + bx * TW + q * 4;

    vf2 stA = {0.f, 0.f}, stB = {0.f, 0.f};   // state (x,y) and (z,w)

    // Double-buffered register window: 2 x 5 rows x 3 chunks.
    vf4 WA[5][3], WB[5][3];

    auto LROW = [&](vf4* R, int bi, int dy) {
        const float* L = &lds[bi][rr * HTW + q * 4 + dy * HTW];
        R[0] = *(const vf4*)(L);
        R[1] = *(const vf4*)(L + 4);
        R[2] = *(const vf4*)(L + 8);
    };

#define SBAR __builtin_amdgcn_sched_barrier(0)

#define FROW(R, DY)                                                   \
    do {                                                              \
        vf4 c0 = (R)[0], c1 = (R)[1], c2 = (R)[2];                    \
        vf2 P0 = {c0.z, c0.w}, P1 = {c1.x, c1.y};                     \
        vf2 P2 = {c1.z, c1.w}, P3 = {c2.x, c2.y};                     \
        const float k0 = kw[(DY) * 5 + 0], k1 = kw[(DY) * 5 + 1];     \
        const float k2 = kw[(DY) * 5 + 2], k3 = kw[(DY) * 5 + 3];     \
        const float k4 = kw[(DY) * 5 + 4];                            \
        const vf2 K01 = {k0, k1}, K23 = {k2, k3}, K40 = {k4, 0.f};    \
        const vf2 K0h = {0.f, k0}, K12 = {k1, k2}, K34 = {k3, k4};    \
        A0 = __builtin_elementwise_fma(K01, P0, A0);                  \
        A0 = __builtin_elementwise_fma(K23, P1, A0);                  \
        A0 = __builtin_elementwise_fma(K40, P2, A0);                  \
        A1 = __builtin_elementwise_fma(K0h, P0, A1);                  \
        A1 = __builtin_elementwise_fma(K12, P1, A1);                  \
        A1 = __builtin_elementwise_fma(K34, P2, A1);                  \
        A2 = __builtin_elementwise_fma(K01, P1, A2);                  \
        A2 = __builtin_elementwise_fma(K23, P2, A2);                  \
        A2 = __builtin_elementwise_fma(K40, P3, A2);                  \
        A3 = __builtin_elementwise_fma(K0h, P1, A3);                  \
        A3 = __builtin_elementwise_fma(K12, P2, A3);                  \
        A3 = __builtin_elementwise_fma(K34, P3, A3);                  \
    } while (0)

#define ENDSTEP(T)                                                    \
    do {                                                              \
        vf4 s = {stA.x, stA.y, stB.x, stB.y};                         \
        __builtin_nontemporal_store(s, (vf4*)(out + (size_t)(T) * HW + obase)); \
        vf2 accA = {A0.x + A0.y, A1.x + A1.y};                        \
        vf2 accB = {A2.x + A2.y, A3.x + A3.y};                        \
        const vf2 m02 = {-0.2f, -0.2f};                               \
        stA = __builtin_elementwise_fma(m02, stA, stA) + accA;        \
        stB = __builtin_elementwise_fma(m02, stB, stB) + accB;        \
    } while (0)

    // Step consuming Wc (this frame) while loading Wn <- buffer BN (next frame).
#define STEP_CL(Wc, Wn, BN, T)                                        \
    do {                                                              \
        vf2 A0 = {0.f, 0.f}, A1 = {0.f, 0.f};                         \
        vf2 A2 = {0.f, 0.f}, A3 = {0.f, 0.f};                         \
        LROW(Wn[0], (BN), 0); SBAR; FROW(Wc[0], 0);                   \
        LROW(Wn[1], (BN), 1); SBAR; FROW(Wc[1], 1);                   \
        LROW(Wn[2], (BN), 2); SBAR; FROW(Wc[2], 2);                   \
        LROW(Wn[3], (BN), 3); SBAR; FROW(Wc[3], 3);                   \
        LROW(Wn[4], (BN), 4); SBAR; FROW(Wc[4], 4);                   \
        ENDSTEP(T);                                                   \
    } while (0)

    // Final step of a group: consume only (next buffer not yet waited).
#define STEP_CO(Wc, T)                                                \
    do {                                                              \
        vf2 A0 = {0.f, 0.f}, A1 = {0.f, 0.f};                         \
        vf2 A2 = {0.f, 0.f}, A3 = {0.f, 0.f};                         \
        FROW(Wc[0], 0); FROW(Wc[1], 1); FROW(Wc[2], 2);               \
        FROW(Wc[3], 3); FROW(Wc[4], 4);                               \
        ENDSTEP(T);                                                   \
    } while (0)

#define LALL(W, B)                                                    \
    do { LROW(W[0], (B), 0); LROW(W[1], (B), 1); LROW(W[2], (B), 2);  \
         LROW(W[3], (B), 3); LROW(W[4], (B), 4); } while (0)

#define GROUP4(B0, B1, B2, B3, T)                                     \
    do {                                                              \
        LALL(WA, (B0));                                               \
        STEP_CL(WA, WB, (B1), (T));                                   \
        STEP_CL(WB, WA, (B2), (T) + 1);                               \
        STEP_CL(WA, WB, (B3), (T) + 2);                               \
        STEP_CO(WB, (T) + 3);                                         \
    } while (0)

    // Prologue: frames 0..7 in flight (16 glds).
    BATCH(0, 0);
    BATCH(4, 4);

    // Group 0 (frames 0..3): outstanding 16, need oldest 8 -> vmcnt(8).
    asm volatile("s_waitcnt vmcnt(8)" ::: "memory");
    GROUP4(0, 1, 2, 3, 0);
    BATCH(8, 8);

    // Steady state: at group top, queue old->new = B_g(8), stores(4),
    // B_{g+1}(8) -> vmcnt(12) drains exactly B_g, never touches stores.
#pragma clang loop unroll(disable)
    for (int sg = 0; sg < 21; ++sg) {
        const int t0 = 4 + sg * 12;
        asm volatile("s_waitcnt vmcnt(12)" ::: "memory");
        GROUP4(4, 5, 6, 7, t0);
        BATCH(0, t0 + 8);
        asm volatile("s_waitcnt vmcnt(12)" ::: "memory");
        GROUP4(8, 9, 10, 11, t0 + 4);
        BATCH(4, t0 + 12);
        asm volatile("s_waitcnt vmcnt(12)" ::: "memory");
        GROUP4(0, 1, 2, 3, t0 + 8);
        BATCH(8, t0 + 16);
    }
#undef GROUP4
#undef LALL
#undef STEP_CO
#undef STEP_CL
#undef ENDSTEP
#undef FROW
#undef SBAR
}

extern "C" void kernel_launch(void* const* d_in, const int* in_sizes, int n_in,
                              void* d_out, int out_size, void* d_ws, size_t ws_size,
                              hipStream_t stream) {
    const float* x = (const float*)d_in[0];      // [256,1,512,512] f32
    const float* kern = (const float*)d_in[1];   // [5,5] f32
    float* out = (float*)d_out;                  // [256,1,512,512] f32

    conv_li_kernel<<<dim3(1024), dim3(64), 0, stream>>>(x, kern, out);
}